// Round 7
// baseline (384.428 us; speedup 1.0000x reference)
//
#include <hip/hip_runtime.h>
#include <cstdint>
#include <cstddef>

#define BB 32
#define NN 1024
#define CIN 128
#define FF 64
#define NOUT 10
#define CAP 128
#define EPSV 1e-5f

// ---------------- fused front: [0,2048) = CSR build (pipelined), [2048,4096) = x@W0 gemm ----------------
// CSR: each wave owns 4 consecutive rows, double-buffered lookahead keeps 2 rows' loads
// in flight -> removes the per-row vmcnt(0) drain that serialized R5/R6 (all-pipes-idle
// signature). W0 staged in 32 KB static LDS (R5 showed W-in-L1 thrashes vs the A-stream).
__global__ __launch_bounds__(256) void k_front(const float* __restrict__ A,
                                               const float* __restrict__ x,
                                               const float* __restrict__ W0,
                                               unsigned short* __restrict__ adj,
                                               int* __restrict__ cnt,
                                               float* __restrict__ c1,
                                               float* __restrict__ c2,
                                               float* __restrict__ T) {
    __shared__ __align__(16) float Wl[CIN * 64];   // 32 KB
    int tid = threadIdx.x;
    int wave = tid >> 6, lane = tid & 63;
    if (blockIdx.x >= 2048) {
        // ---- gemm: T[row, f] = sum_k x[row,k] * W0[k,f], 16 rows per block ----
        int gid = blockIdx.x - 2048;        // 2048%8==0 -> XCD gid%8 == b%8, matches spmm
        int b = gid & 31;
        int cch = gid >> 5;                 // chunk in [0,64)
        int row0 = (b << 10) + cch * 16;
        for (int t = tid; t < CIN * 16; t += 256)
            ((float4*)Wl)[t] = ((const float4*)W0)[t];
        __syncthreads();
        int rsub = lane >> 4, f0 = (lane & 15) * 4;
        int r = row0 + wave * 4 + rsub;
        const float4* xr = (const float4*)(x + (size_t)r * CIN);
        float4 acc = {0.f, 0.f, 0.f, 0.f};
#pragma unroll 4
        for (int k4 = 0; k4 < CIN / 4; ++k4) {
            float4 xv = xr[k4];                       // broadcast within 16-lane group
            float4 w0 = *(const float4*)&Wl[(k4 * 4 + 0) * 64 + f0];
            float4 w1 = *(const float4*)&Wl[(k4 * 4 + 1) * 64 + f0];
            float4 w2 = *(const float4*)&Wl[(k4 * 4 + 2) * 64 + f0];
            float4 w3 = *(const float4*)&Wl[(k4 * 4 + 3) * 64 + f0];
            acc.x += xv.x * w0.x; acc.y += xv.x * w0.y; acc.z += xv.x * w0.z; acc.w += xv.x * w0.w;
            acc.x += xv.y * w1.x; acc.y += xv.y * w1.y; acc.z += xv.y * w1.z; acc.w += xv.y * w1.w;
            acc.x += xv.z * w2.x; acc.y += xv.z * w2.y; acc.z += xv.z * w2.z; acc.w += xv.z * w2.w;
            acc.x += xv.w * w3.x; acc.y += xv.w * w3.y; acc.z += xv.w * w3.z; acc.w += xv.w * w3.w;
        }
        *(float4*)&T[(size_t)r * 64 + f0] = acc;
    } else {
        // ---- CSR build: wave per row, ballot prefix-compaction (ascending j) ----
        unsigned long long lt = (lane == 0) ? 0ULL : ((1ULL << lane) - 1ULL);
        auto rowp = [&](int rr) { return (const float4*)(A + (size_t)rr * NN); };
        auto process = [&](int rr, float4 v0, float4 v1, float4 v2, float4 v3) {
            size_t base = (size_t)rr * CAP;
            int c = 0;
            float4 vv[4] = {v0, v1, v2, v3};
#pragma unroll
            for (int it = 0; it < 4; ++it) {
                float4 v = vv[it];
                int j0 = it * 256 + lane * 4;
                unsigned long long m0 = __ballot(v.x != 0.f);
                unsigned long long m1 = __ballot(v.y != 0.f);
                unsigned long long m2 = __ballot(v.z != 0.f);
                unsigned long long m3 = __ballot(v.w != 0.f);
                int before = __popcll(m0 & lt) + __popcll(m1 & lt) +
                             __popcll(m2 & lt) + __popcll(m3 & lt);
                int p = c + before;
                if (v.x != 0.f) { if (p < CAP) adj[base + p] = (unsigned short)(j0 + 0); ++p; }
                if (v.y != 0.f) { if (p < CAP) adj[base + p] = (unsigned short)(j0 + 1); ++p; }
                if (v.z != 0.f) { if (p < CAP) adj[base + p] = (unsigned short)(j0 + 2); ++p; }
                if (v.w != 0.f) { if (p < CAP) adj[base + p] = (unsigned short)(j0 + 3); ++p; }
                c += __popcll(m0) + __popcll(m1) + __popcll(m2) + __popcll(m3);
            }
            if (lane == 0) {
                cnt[rr] = (c > CAP) ? CAP : c;
                float D = 1.0f / sqrtf((float)c + 1.0f + EPSV);
                c1[rr] = D;
                c2[rr] = D * D;
            }
        };
        int gw = blockIdx.x * 4 + wave;      // global wave in [0,8192)
        int r0 = gw * 4;                     // 4 consecutive rows per wave
        // double-buffered lookahead: rows r0,r0+2 in buf a; r0+1,r0+3 in buf b
        const float4* p0 = rowp(r0);
        float4 a0 = p0[lane], a1 = p0[64 + lane], a2 = p0[128 + lane], a3 = p0[192 + lane];
        const float4* p1 = rowp(r0 + 1);
        float4 b0 = p1[lane], b1 = p1[64 + lane], b2 = p1[128 + lane], b3 = p1[192 + lane];
        process(r0, a0, a1, a2, a3);
        const float4* p2 = rowp(r0 + 2);
        a0 = p2[lane]; a1 = p2[64 + lane]; a2 = p2[128 + lane]; a3 = p2[192 + lane];
        process(r0 + 1, b0, b1, b2, b3);
        const float4* p3 = rowp(r0 + 3);
        b0 = p3[lane]; b1 = p3[64 + lane]; b2 = p3[128 + lane]; b3 = p3[192 + lane];
        process(r0 + 2, a0, a1, a2, a3);
        process(r0 + 3, b0, b1, b2, b3);
    }
}

// ---------------- fused mid: [0,8192) = deg, [8192,10240) = gemm64 (scaled) ----------------
// W in 16 KB static LDS; deg blocks first (latency-bound part starts at t=0).
__global__ __launch_bounds__(256) void k_mid(const unsigned short* __restrict__ adj,
                                             const int* __restrict__ cnt,
                                             const float* __restrict__ nm,
                                             float* __restrict__ c1, float* __restrict__ c2,
                                             const float* __restrict__ Xin,
                                             const float* __restrict__ W,
                                             const float* __restrict__ y,
                                             float* __restrict__ T) {
    __shared__ __align__(16) float Wl[64 * 64];    // 16 KB
    int tid = threadIdx.x;
    if (blockIdx.x >= 8192) {
        // ---- gemm64 with tanh(y)*nm row-scale ----
        int gid = blockIdx.x - 8192;
        int b = gid & 31;                   // XCD matches spmm reader
        int cch = gid >> 5;
        int row0 = (b << 10) + cch * 16;
        for (int t = tid; t < 64 * 16; t += 256)
            ((float4*)Wl)[t] = ((const float4*)W)[t];
        __syncthreads();
        int wave = tid >> 6, lane = tid & 63;
        int rsub = lane >> 4, f0 = (lane & 15) * 4;
        int r = row0 + wave * 4 + rsub;
        float sc = tanhf(y[r]) * nm[r];     // same value across the 16-lane group
        const float4* xr = (const float4*)(Xin + (size_t)r * 64);
        float4 acc = {0.f, 0.f, 0.f, 0.f};
#pragma unroll 4
        for (int k4 = 0; k4 < 16; ++k4) {
            float4 xv = xr[k4];
            float4 w0 = *(const float4*)&Wl[(k4 * 4 + 0) * 64 + f0];
            float4 w1 = *(const float4*)&Wl[(k4 * 4 + 1) * 64 + f0];
            float4 w2 = *(const float4*)&Wl[(k4 * 4 + 2) * 64 + f0];
            float4 w3 = *(const float4*)&Wl[(k4 * 4 + 3) * 64 + f0];
            acc.x += xv.x * w0.x; acc.y += xv.x * w0.y; acc.z += xv.x * w0.z; acc.w += xv.x * w0.w;
            acc.x += xv.y * w1.x; acc.y += xv.y * w1.y; acc.z += xv.y * w1.z; acc.w += xv.y * w1.w;
            acc.x += xv.z * w2.x; acc.y += xv.z * w2.y; acc.z += xv.z * w2.z; acc.w += xv.z * w2.w;
            acc.x += xv.w * w3.x; acc.y += xv.w * w3.y; acc.z += xv.w * w3.z; acc.w += xv.w * w3.w;
        }
        acc.x *= sc; acc.y *= sc; acc.z *= sc; acc.w *= sc;
        *(float4*)&T[(size_t)r * 64 + f0] = acc;
    } else {
        // ---- masked degree, wave per row (nm entries are 0/1 -> order-exact) ----
        int wave = tid >> 6, lane = tid & 63;
        int r = blockIdx.x * 4 + wave;
        int b = r >> 10;
        const unsigned short* arow = adj + (size_t)r * CAP;
        const float* nmb = nm + (b << 10);
        int n = cnt[r];
        float s = 0.f;
        if (lane < n)      s  = nmb[arow[lane]];
        if (lane + 64 < n) s += nmb[arow[lane + 64]];
        for (int sh = 32; sh; sh >>= 1) s += __shfl_xor(s, sh, 64);
        if (lane == 0) {
            float m = nm[r];
            float D = 1.0f / sqrtf(m * s + 1.0f + EPSV);
            c1[r] = m * D;
            c2[r] = D * D;
        }
    }
}

// ---------------- SpMM + self + bias + relu (+ fused pool score) ----------------
// XCD swizzle: blockIdx = c*32 + b keeps graph b's T gathers on XCD b%8's L2.
// c1 staged in LDS (broadcast reads, free). 4-unrolled independent gather chains.
__global__ __launch_bounds__(256) void k_spmm(const unsigned short* __restrict__ adj,
                                              const int* __restrict__ cnt,
                                              const float* __restrict__ c1,
                                              const float* __restrict__ c2,
                                              const float* __restrict__ T,
                                              const float* __restrict__ bias,
                                              float* __restrict__ X,
                                              const float* __restrict__ p,
                                              float* __restrict__ y) {
    __shared__ __align__(16) float c1s[NN];
    int b   = blockIdx.x & 31;            // graph
    int cch = blockIdx.x >> 5;            // chunk in [0,256)
    int tid = threadIdx.x;
    ((float4*)c1s)[tid] = ((const float4*)(c1 + (b << 10)))[tid];
    __syncthreads();
    int wave = tid >> 6, lane = tid & 63;
    int r = (b << 10) + cch * 4 + wave;
    const unsigned short* arow = adj + (size_t)r * CAP;
    int n = cnt[r];
    const float* Tb = T + ((size_t)(b << 10) << 6);
    float acc0 = 0.f, acc1 = 0.f, acc2 = 0.f, acc3 = 0.f;
    int t = 0;
    for (; t + 4 <= n; t += 4) {
        ushort4 j4 = *(const ushort4*)(arow + t);
        acc0 += c1s[j4.x] * Tb[((int)j4.x << 6) + lane];
        acc1 += c1s[j4.y] * Tb[((int)j4.y << 6) + lane];
        acc2 += c1s[j4.z] * Tb[((int)j4.z << 6) + lane];
        acc3 += c1s[j4.w] * Tb[((int)j4.w << 6) + lane];
    }
    for (; t < n; ++t) {
        int j = arow[t];
        acc0 += c1s[j] * Tb[(j << 6) + lane];
    }
    float acc = (acc0 + acc1) + (acc2 + acc3);
    int rl = r & 1023;
    float o = c1s[rl] * acc + c2[r] * T[((size_t)r << 6) + lane] + bias[lane];
    o = fmaxf(o, 0.f);
    X[((size_t)r << 6) + lane] = o;
    if (p != nullptr) {
        float pv = p[lane];
        float a = o * pv;
        float pp = pv * pv;
        for (int s = 32; s; s >>= 1) {
            a += __shfl_xor(a, s, 64);
            pp += __shfl_xor(pp, s, 64);
        }
        if (lane == 0) y[r] = a / sqrtf(pp);
    }
}

// ---------------- pool ranking: stable-argsort semantics, 16 blocks/graph ----------------
__global__ __launch_bounds__(256) void k_rank(const float* __restrict__ y,
                                              const float* __restrict__ maskSrc,
                                              const int* __restrict__ nsrc,
                                              float* __restrict__ nmOut,
                                              int* __restrict__ ncur) {
    __shared__ __align__(16) float yv[NN];
    int b = blockIdx.x >> 4;       // 16 blocks per graph
    int sub = blockIdx.x & 15;
    int tid = threadIdx.x;
    const float INF = __builtin_inff();
    {
        float4 v = ((const float4*)(y + (b << 10)))[tid];
        float4 m = ((const float4*)(maskSrc + (b << 10)))[tid];
        v.x = (m.x > 0.f) ? v.x : INF;
        v.y = (m.y > 0.f) ? v.y : INF;
        v.z = (m.z > 0.f) ? v.z : INF;
        v.w = (m.w > 0.f) ? v.w : INF;
        ((float4*)yv)[tid] = v;
    }
    int n = nsrc[b];
    const float RM = (float)(1.0 - 0.8);   // 0.2f, matches jax f32 semantics
    int nrem = (int)((float)n * RM);
    if (sub == 0 && tid == 0) ncur[b] = n - nrem;
    __syncthreads();
    int i = (sub << 6) + (tid >> 2);       // 64 nodes per block, 4 threads per node
    int q = tid & 3;                       // quarter of the j-range
    float yi = yv[i];
    int rank = 0;
    if (yi < INF) {
        const float4* jbase = (const float4*)yv + (q << 6);
        int j0 = q << 8;
#pragma unroll 8
        for (int t = 0; t < 64; ++t) {
            float4 a = jbase[t];
            int j = j0 + t * 4;
            rank += (a.x < yi || (a.x == yi && j     < i)) ? 1 : 0;
            rank += (a.y < yi || (a.y == yi && j + 1 < i)) ? 1 : 0;
            rank += (a.z < yi || (a.z == yi && j + 2 < i)) ? 1 : 0;
            rank += (a.w < yi || (a.w == yi && j + 3 < i)) ? 1 : 0;
        }
    }
    rank += __shfl_xor(rank, 1, 64);
    rank += __shfl_xor(rank, 2, 64);
    if (q == 0) {
        float nmv = (yi < INF && rank >= nrem) ? 1.f : 0.f;
        nmOut[(b << 10) + i] = nmv;
    }
}

// ---------------- global max over nodes + final fc (block b -> XCD b%8, matches X writer) ----------------
__global__ __launch_bounds__(256) void k_final(const float* __restrict__ X,
                                               const float* __restrict__ Wfc,
                                               const float* __restrict__ bfc,
                                               float* __restrict__ out) {
    __shared__ float red[4][64];
    __shared__ float gl[64];
    int b = blockIdx.x, tid = threadIdx.x;
    int f = tid & 63, c = tid >> 6;
    float m = 0.f;  // all values are post-relu >= 0
    for (int i = c; i < NN; i += 4)
        m = fmaxf(m, X[(((size_t)(b << 10) + i) << 6) + f]);
    red[c][f] = m;
    __syncthreads();
    if (tid < 64)
        gl[tid] = fmaxf(fmaxf(red[0][tid], red[1][tid]), fmaxf(red[2][tid], red[3][tid]));
    __syncthreads();
    if (tid < NOUT) {
        float acc = bfc[tid];
        for (int k = 0; k < 64; ++k) acc += gl[k] * Wfc[k * NOUT + tid];
        out[b * NOUT + tid] = acc;
    }
}

extern "C" void kernel_launch(void* const* d_in, const int* in_sizes, int n_in,
                              void* d_out, int out_size, void* d_ws, size_t ws_size,
                              hipStream_t stream) {
    const float* x    = (const float*)d_in[0];
    const float* A    = (const float*)d_in[1];
    const float* mask = (const float*)d_in[2];
    const int*   Nn   = (const int*)d_in[3];
    const float* W0   = (const float*)d_in[4];
    const float* b0   = (const float*)d_in[5];
    const float* W1   = (const float*)d_in[6];
    const float* b1   = (const float*)d_in[7];
    const float* W2   = (const float*)d_in[8];
    const float* b2   = (const float*)d_in[9];
    const float* p0   = (const float*)d_in[10];
    const float* p1   = (const float*)d_in[11];
    const float* Wfc  = (const float*)d_in[12];
    const float* bfc  = (const float*)d_in[13];
    float* out = (float*)d_out;

    char* ws = (char*)d_ws;
    size_t off = 0;
    auto alloc = [&](size_t bytes) -> void* {
        void* p = ws + off;
        off = (off + bytes + 255) & ~(size_t)255;
        return p;
    };
    unsigned short* adj = (unsigned short*)alloc((size_t)BB * NN * CAP * 2);
    int*   cnt  = (int*)  alloc((size_t)BB * NN * 4);
    float* X    = (float*)alloc((size_t)BB * NN * 64 * 4);
    float* T    = (float*)alloc((size_t)BB * NN * 64 * 4);
    float* c1   = (float*)alloc((size_t)BB * NN * 4);
    float* c2   = (float*)alloc((size_t)BB * NN * 4);
    float* y    = (float*)alloc((size_t)BB * NN * 4);
    float* nm0  = (float*)alloc((size_t)BB * NN * 4);
    float* nm1  = (float*)alloc((size_t)BB * NN * 4);
    int*   nc0  = (int*)  alloc((size_t)BB * 4);
    int*   nc1  = (int*)  alloc((size_t)BB * 4);

    const int RW = BB * NN;       // 32768 rows
    // 1) fused: CSR build (2048 blocks, pipelined 4 rows/wave, dispatched first)
    //    + x@W0 gemm (2048 blocks, XCD-aligned)
    k_front<<<2048 + 2048, 256, 0, stream>>>(A, x, W0, adj, cnt, c1, c2, T);
    // 2) layer 1 SpMM (+ pool-1 score), XCD-swizzled
    k_spmm<<<RW / 4, 256, 0, stream>>>(adj, cnt, c1, c2, T, b0, X, p0, y);
    // pool 1
    k_rank<<<BB * 16, 256, 0, stream>>>(y, mask, Nn, nm0, nc0);
    // 3) layer 2: fused deg (first) + gemm64
    k_mid<<<8192 + 2048, 256, 0, stream>>>(adj, cnt, nm0, c1, c2, X, W1, y, T);
    k_spmm<<<RW / 4, 256, 0, stream>>>(adj, cnt, c1, c2, T, b1, X, p1, y);
    // pool 2 (double-buffered mask)
    k_rank<<<BB * 16, 256, 0, stream>>>(y, nm0, nc0, nm1, nc1);
    // 4) layer 3: fused deg (first) + gemm64
    k_mid<<<8192 + 2048, 256, 0, stream>>>(adj, cnt, nm1, c1, c2, X, W2, y, T);
    k_spmm<<<RW / 4, 256, 0, stream>>>(adj, cnt, c1, c2, T, b2, X, nullptr, nullptr);
    // 5) global max pool + fc
    k_final<<<BB, 256, 0, stream>>>(X, Wfc, bfc, out);
}

// Round 8
// 373.847 us; speedup vs baseline: 1.0283x; 1.0283x over previous
//
#include <hip/hip_runtime.h>
#include <cstdint>
#include <cstddef>

#define BB 32
#define NN 1024
#define CIN 128
#define FF 64
#define NOUT 10
#define CAP 128
#define EPSV 1e-5f

// ---------------- fused front: [0,8192) = CSR build, [8192,10240) = x@W0 gemm ----------------
// CSR first (latency-bound A-scan starts at t=0). Compacted row staged in LDS (scattered
// ds_write_b16), flushed as ONE coalesced u32 store per row (was ~23 scattered 2B global
// stores). LDS for staging aliases the gemm path's Wl (CSR blocks never use Wl).
__global__ __launch_bounds__(256) void k_front(const float* __restrict__ A,
                                               const float* __restrict__ x,
                                               const float* __restrict__ W0,
                                               unsigned short* __restrict__ adj,
                                               int* __restrict__ cnt,
                                               float* __restrict__ c1,
                                               float* __restrict__ c2,
                                               float* __restrict__ T) {
    __shared__ __align__(16) float Wl[CIN * 64];   // 32 KB (gemm); CSR aliases 1 KB of it
    int tid = threadIdx.x;
    int wave = tid >> 6, lane = tid & 63;
    if (blockIdx.x >= 8192) {
        // ---- gemm: T[row, f] = sum_k x[row,k] * W0[k,f], 16 rows per block ----
        int gid = blockIdx.x - 8192;        // 8192%8==0 -> XCD gid%8 == b%8, matches spmm
        int b = gid & 31;
        int cch = gid >> 5;                 // chunk in [0,64)
        int row0 = (b << 10) + cch * 16;
        for (int t = tid; t < CIN * 16; t += 256)
            ((float4*)Wl)[t] = ((const float4*)W0)[t];
        __syncthreads();
        int rsub = lane >> 4, f0 = (lane & 15) * 4;
        int r = row0 + wave * 4 + rsub;
        const float4* xr = (const float4*)(x + (size_t)r * CIN);
        float4 acc = {0.f, 0.f, 0.f, 0.f};
#pragma unroll 4
        for (int k4 = 0; k4 < CIN / 4; ++k4) {
            float4 xv = xr[k4];                       // broadcast within 16-lane group
            float4 w0 = *(const float4*)&Wl[(k4 * 4 + 0) * 64 + f0];
            float4 w1 = *(const float4*)&Wl[(k4 * 4 + 1) * 64 + f0];
            float4 w2 = *(const float4*)&Wl[(k4 * 4 + 2) * 64 + f0];
            float4 w3 = *(const float4*)&Wl[(k4 * 4 + 3) * 64 + f0];
            acc.x += xv.x * w0.x; acc.y += xv.x * w0.y; acc.z += xv.x * w0.z; acc.w += xv.x * w0.w;
            acc.x += xv.y * w1.x; acc.y += xv.y * w1.y; acc.z += xv.y * w1.z; acc.w += xv.y * w1.w;
            acc.x += xv.z * w2.x; acc.y += xv.z * w2.y; acc.z += xv.z * w2.z; acc.w += xv.z * w2.w;
            acc.x += xv.w * w3.x; acc.y += xv.w * w3.y; acc.z += xv.w * w3.z; acc.w += xv.w * w3.w;
        }
        *(float4*)&T[(size_t)r * 64 + f0] = acc;
    } else {
        // ---- CSR build: wave per row, ballot prefix-compaction (ascending j) ----
        unsigned short* adjs = ((unsigned short*)Wl) + wave * CAP;   // 256 B per wave
        int r = blockIdx.x * 4 + wave;                 // global row in [0, B*N)
        const float4* Arow = (const float4*)(A + (size_t)r * NN);
        // issue all 4 independent loads up front (one vmcnt drain covers all)
        float4 v0 = Arow[lane];
        float4 v1 = Arow[64 + lane];
        float4 v2 = Arow[128 + lane];
        float4 v3 = Arow[192 + lane];
        int c = 0;
        unsigned long long lt = (lane == 0) ? 0ULL : ((1ULL << lane) - 1ULL);
        float4 vv[4] = {v0, v1, v2, v3};
#pragma unroll
        for (int it = 0; it < 4; ++it) {
            float4 v = vv[it];
            int j0 = it * 256 + lane * 4;
            unsigned long long m0 = __ballot(v.x != 0.f);
            unsigned long long m1 = __ballot(v.y != 0.f);
            unsigned long long m2 = __ballot(v.z != 0.f);
            unsigned long long m3 = __ballot(v.w != 0.f);
            int before = __popcll(m0 & lt) + __popcll(m1 & lt) +
                         __popcll(m2 & lt) + __popcll(m3 & lt);
            int p = c + before;
            if (v.x != 0.f) { if (p < CAP) adjs[p] = (unsigned short)(j0 + 0); ++p; }
            if (v.y != 0.f) { if (p < CAP) adjs[p] = (unsigned short)(j0 + 1); ++p; }
            if (v.z != 0.f) { if (p < CAP) adjs[p] = (unsigned short)(j0 + 2); ++p; }
            if (v.w != 0.f) { if (p < CAP) adjs[p] = (unsigned short)(j0 + 3); ++p; }
            c += __popcll(m0) + __popcll(m1) + __popcll(m2) + __popcll(m3);
        }
        int cc = (c > CAP) ? CAP : c;
        // coalesced flush: one u32 per lane covers 2 entries
        uint32_t* dst = (uint32_t*)(adj + (size_t)r * CAP);
        if (lane * 2 < cc) dst[lane] = ((const uint32_t*)adjs)[lane];
        if (lane == 0) {
            cnt[r] = cc;
            float D = 1.0f / sqrtf((float)c + 1.0f + EPSV);
            c1[r] = D;
            c2[r] = D * D;
        }
    }
}

// ---------------- fused mid: [0,8192) = deg, [8192,10240) = gemm64 (scaled) ----------------
// W in 16 KB static LDS; deg blocks first (latency-bound part starts at t=0).
__global__ __launch_bounds__(256) void k_mid(const unsigned short* __restrict__ adj,
                                             const int* __restrict__ cnt,
                                             const float* __restrict__ nm,
                                             float* __restrict__ c1, float* __restrict__ c2,
                                             const float* __restrict__ Xin,
                                             const float* __restrict__ W,
                                             const float* __restrict__ y,
                                             float* __restrict__ T) {
    __shared__ __align__(16) float Wl[64 * 64];    // 16 KB
    int tid = threadIdx.x;
    if (blockIdx.x >= 8192) {
        // ---- gemm64 with tanh(y)*nm row-scale ----
        int gid = blockIdx.x - 8192;
        int b = gid & 31;                   // XCD matches spmm reader
        int cch = gid >> 5;
        int row0 = (b << 10) + cch * 16;
        for (int t = tid; t < 64 * 16; t += 256)
            ((float4*)Wl)[t] = ((const float4*)W)[t];
        __syncthreads();
        int wave = tid >> 6, lane = tid & 63;
        int rsub = lane >> 4, f0 = (lane & 15) * 4;
        int r = row0 + wave * 4 + rsub;
        float sc = tanhf(y[r]) * nm[r];     // same value across the 16-lane group
        const float4* xr = (const float4*)(Xin + (size_t)r * 64);
        float4 acc = {0.f, 0.f, 0.f, 0.f};
#pragma unroll 4
        for (int k4 = 0; k4 < 16; ++k4) {
            float4 xv = xr[k4];
            float4 w0 = *(const float4*)&Wl[(k4 * 4 + 0) * 64 + f0];
            float4 w1 = *(const float4*)&Wl[(k4 * 4 + 1) * 64 + f0];
            float4 w2 = *(const float4*)&Wl[(k4 * 4 + 2) * 64 + f0];
            float4 w3 = *(const float4*)&Wl[(k4 * 4 + 3) * 64 + f0];
            acc.x += xv.x * w0.x; acc.y += xv.x * w0.y; acc.z += xv.x * w0.z; acc.w += xv.x * w0.w;
            acc.x += xv.y * w1.x; acc.y += xv.y * w1.y; acc.z += xv.y * w1.z; acc.w += xv.y * w1.w;
            acc.x += xv.z * w2.x; acc.y += xv.z * w2.y; acc.z += xv.z * w2.z; acc.w += xv.z * w2.w;
            acc.x += xv.w * w3.x; acc.y += xv.w * w3.y; acc.z += xv.w * w3.z; acc.w += xv.w * w3.w;
        }
        acc.x *= sc; acc.y *= sc; acc.z *= sc; acc.w *= sc;
        *(float4*)&T[(size_t)r * 64 + f0] = acc;
    } else {
        // ---- masked degree, wave per row (nm entries are 0/1 -> order-exact) ----
        int wave = tid >> 6, lane = tid & 63;
        int r = blockIdx.x * 4 + wave;
        int b = r >> 10;
        const unsigned short* arow = adj + (size_t)r * CAP;
        const float* nmb = nm + (b << 10);
        int n = cnt[r];
        float s = 0.f;
        if (lane < n)      s  = nmb[arow[lane]];
        if (lane + 64 < n) s += nmb[arow[lane + 64]];
        for (int sh = 32; sh; sh >>= 1) s += __shfl_xor(s, sh, 64);
        if (lane == 0) {
            float m = nm[r];
            float D = 1.0f / sqrtf(m * s + 1.0f + EPSV);
            c1[r] = m * D;
            c2[r] = D * D;
        }
    }
}

// ---------------- SpMM + self + bias + relu (+ pool score OR fused global max) ----------------
// 2048 blocks, 16 rows/block (wave does 4 sequential rows) -> c1s staging amortized 4x.
// XCD swizzle: blockIdx = cch*32 + b keeps graph b's T gathers on XCD b%8's L2.
__global__ __launch_bounds__(256) void k_spmm(const unsigned short* __restrict__ adj,
                                              const int* __restrict__ cnt,
                                              const float* __restrict__ c1,
                                              const float* __restrict__ c2,
                                              const float* __restrict__ T,
                                              const float* __restrict__ bias,
                                              float* __restrict__ X,
                                              const float* __restrict__ p,
                                              float* __restrict__ y,
                                              float* __restrict__ gmax) {
    __shared__ __align__(16) float c1s[NN];
    __shared__ float red[4][64];
    int b   = blockIdx.x & 31;            // graph
    int cch = blockIdx.x >> 5;            // chunk in [0,64)
    int tid = threadIdx.x;
    ((float4*)c1s)[tid] = ((const float4*)(c1 + (b << 10)))[tid];
    __syncthreads();
    int wave = tid >> 6, lane = tid & 63;
    int r0 = (b << 10) + cch * 16 + wave * 4;
    const float* Tb = T + ((size_t)(b << 10) << 6);
    float bv = bias[lane];
    float pv = 0.f, ppinv = 0.f;
    if (p != nullptr) {
        pv = p[lane];
        float pp = pv * pv;
        for (int s = 32; s; s >>= 1) pp += __shfl_xor(pp, s, 64);
        ppinv = 1.0f / sqrtf(pp);
    }
    float vmax = 0.f;
#pragma unroll
    for (int rr = 0; rr < 4; ++rr) {
        int r = r0 + rr;
        const unsigned short* arow = adj + (size_t)r * CAP;
        int n = cnt[r];
        float acc0 = 0.f, acc1 = 0.f, acc2 = 0.f, acc3 = 0.f;
        int t = 0;
        for (; t + 4 <= n; t += 4) {
            ushort4 j4 = *(const ushort4*)(arow + t);
            acc0 += c1s[j4.x] * Tb[((int)j4.x << 6) + lane];
            acc1 += c1s[j4.y] * Tb[((int)j4.y << 6) + lane];
            acc2 += c1s[j4.z] * Tb[((int)j4.z << 6) + lane];
            acc3 += c1s[j4.w] * Tb[((int)j4.w << 6) + lane];
        }
        for (; t < n; ++t) {
            int j = arow[t];
            acc0 += c1s[j] * Tb[(j << 6) + lane];
        }
        float acc = (acc0 + acc1) + (acc2 + acc3);
        int rl = r & 1023;
        float o = c1s[rl] * acc + c2[r] * T[((size_t)r << 6) + lane] + bv;
        o = fmaxf(o, 0.f);
        if (X != nullptr) X[((size_t)r << 6) + lane] = o;
        if (p != nullptr) {
            float a = o * pv;
            for (int s = 32; s; s >>= 1) a += __shfl_xor(a, s, 64);
            if (lane == 0) y[r] = a * ppinv;
        }
        vmax = fmaxf(vmax, o);
    }
    if (gmax != nullptr) {
        red[wave][lane] = vmax;
        __syncthreads();
        if (wave == 0) {
            float m = fmaxf(fmaxf(red[0][lane], red[1][lane]),
                            fmaxf(red[2][lane], red[3][lane]));
            // all values >= 0: int compare of float bits preserves order; gmax pre-zeroed
            atomicMax((int*)&gmax[(b << 6) + lane], __float_as_int(m));
        }
    }
}

// ---------------- pool ranking: stable-argsort semantics, 16 blocks/graph ----------------
__global__ __launch_bounds__(256) void k_rank(const float* __restrict__ y,
                                              const float* __restrict__ maskSrc,
                                              const int* __restrict__ nsrc,
                                              float* __restrict__ nmOut,
                                              int* __restrict__ ncur) {
    __shared__ __align__(16) float yv[NN];
    int b = blockIdx.x >> 4;       // 16 blocks per graph
    int sub = blockIdx.x & 15;
    int tid = threadIdx.x;
    const float INF = __builtin_inff();
    {
        float4 v = ((const float4*)(y + (b << 10)))[tid];
        float4 m = ((const float4*)(maskSrc + (b << 10)))[tid];
        v.x = (m.x > 0.f) ? v.x : INF;
        v.y = (m.y > 0.f) ? v.y : INF;
        v.z = (m.z > 0.f) ? v.z : INF;
        v.w = (m.w > 0.f) ? v.w : INF;
        ((float4*)yv)[tid] = v;
    }
    int n = nsrc[b];
    const float RM = (float)(1.0 - 0.8);   // 0.2f, matches jax f32 semantics
    int nrem = (int)((float)n * RM);
    if (sub == 0 && tid == 0) ncur[b] = n - nrem;
    __syncthreads();
    int i = (sub << 6) + (tid >> 2);       // 64 nodes per block, 4 threads per node
    int q = tid & 3;                       // quarter of the j-range
    float yi = yv[i];
    int rank = 0;
    if (yi < INF) {
        const float4* jbase = (const float4*)yv + (q << 6);
        int j0 = q << 8;
#pragma unroll 8
        for (int t = 0; t < 64; ++t) {
            float4 a = jbase[t];
            int j = j0 + t * 4;
            rank += (a.x < yi || (a.x == yi && j     < i)) ? 1 : 0;
            rank += (a.y < yi || (a.y == yi && j + 1 < i)) ? 1 : 0;
            rank += (a.z < yi || (a.z == yi && j + 2 < i)) ? 1 : 0;
            rank += (a.w < yi || (a.w == yi && j + 3 < i)) ? 1 : 0;
        }
    }
    rank += __shfl_xor(rank, 1, 64);
    rank += __shfl_xor(rank, 2, 64);
    if (q == 0) {
        float nmv = (yi < INF && rank >= nrem) ? 1.f : 0.f;
        nmOut[(b << 10) + i] = nmv;
    }
}

// ---------------- final fc from the fused global-max buffer ----------------
__global__ __launch_bounds__(64) void k_fc(const float* __restrict__ gmax,
                                           const float* __restrict__ Wfc,
                                           const float* __restrict__ bfc,
                                           float* __restrict__ out) {
    __shared__ float gl[64];
    int b = blockIdx.x, lane = threadIdx.x;
    gl[lane] = gmax[(b << 6) + lane];
    __syncthreads();
    if (lane < NOUT) {
        float acc = bfc[lane];
        for (int k = 0; k < 64; ++k) acc += gl[k] * Wfc[k * NOUT + lane];
        out[b * NOUT + lane] = acc;
    }
}

extern "C" void kernel_launch(void* const* d_in, const int* in_sizes, int n_in,
                              void* d_out, int out_size, void* d_ws, size_t ws_size,
                              hipStream_t stream) {
    const float* x    = (const float*)d_in[0];
    const float* A    = (const float*)d_in[1];
    const float* mask = (const float*)d_in[2];
    const int*   Nn   = (const int*)d_in[3];
    const float* W0   = (const float*)d_in[4];
    const float* b0   = (const float*)d_in[5];
    const float* W1   = (const float*)d_in[6];
    const float* b1   = (const float*)d_in[7];
    const float* W2   = (const float*)d_in[8];
    const float* b2   = (const float*)d_in[9];
    const float* p0   = (const float*)d_in[10];
    const float* p1   = (const float*)d_in[11];
    const float* Wfc  = (const float*)d_in[12];
    const float* bfc  = (const float*)d_in[13];
    float* out = (float*)d_out;

    char* ws = (char*)d_ws;
    size_t off = 0;
    auto alloc = [&](size_t bytes) -> void* {
        void* p = ws + off;
        off = (off + bytes + 255) & ~(size_t)255;
        return p;
    };
    unsigned short* adj = (unsigned short*)alloc((size_t)BB * NN * CAP * 2);
    int*   cnt  = (int*)  alloc((size_t)BB * NN * 4);
    float* X    = (float*)alloc((size_t)BB * NN * 64 * 4);
    float* T    = (float*)alloc((size_t)BB * NN * 64 * 4);
    float* c1   = (float*)alloc((size_t)BB * NN * 4);
    float* c2   = (float*)alloc((size_t)BB * NN * 4);
    float* y    = (float*)alloc((size_t)BB * NN * 4);
    float* nm0  = (float*)alloc((size_t)BB * NN * 4);
    float* nm1  = (float*)alloc((size_t)BB * NN * 4);
    int*   nc0  = (int*)  alloc((size_t)BB * 4);
    int*   nc1  = (int*)  alloc((size_t)BB * 4);
    float* gmax = (float*)alloc((size_t)BB * 64 * 4);

    const int RW = BB * NN;       // 32768 rows
    // zero the fused-max buffer (ws is poisoned 0xAA before every call)
    hipMemsetAsync(gmax, 0, (size_t)BB * 64 * 4, stream);
    // 1) fused: CSR build (8192 blocks, LDS-staged coalesced adj flush) + x@W0 gemm
    k_front<<<8192 + 2048, 256, 0, stream>>>(A, x, W0, adj, cnt, c1, c2, T);
    // 2) layer 1 SpMM (+ pool-1 score)
    k_spmm<<<2048, 256, 0, stream>>>(adj, cnt, c1, c2, T, b0, X, p0, y, nullptr);
    // pool 1
    k_rank<<<BB * 16, 256, 0, stream>>>(y, mask, Nn, nm0, nc0);
    // 3) layer 2: fused deg (first) + gemm64
    k_mid<<<8192 + 2048, 256, 0, stream>>>(adj, cnt, nm0, c1, c2, X, W1, y, T);
    k_spmm<<<2048, 256, 0, stream>>>(adj, cnt, c1, c2, T, b1, X, p1, y, nullptr);
    // pool 2 (double-buffered mask)
    k_rank<<<BB * 16, 256, 0, stream>>>(y, nm0, nc0, nm1, nc1);
    // 4) layer 3: fused deg (first) + gemm64; spmm fuses global max (no X write)
    k_mid<<<8192 + 2048, 256, 0, stream>>>(adj, cnt, nm1, c1, c2, X, W2, y, T);
    k_spmm<<<2048, 256, 0, stream>>>(adj, cnt, c1, c2, T, b2, nullptr, nullptr, nullptr, gmax);
    // 5) fc from gmax
    k_fc<<<BB, 64, 0, stream>>>(gmax, Wfc, bfc, out);
}